// Round 4
// baseline (33.241 us; speedup 1.0000x reference)
//
#include <hip/hip_runtime.h>
#include <math.h>

#define NE 16
#define ND 5
#define NB 8
#define NP 65536
#define EDIM 128
#define NBETAS 4

typedef float f32x4 __attribute__((ext_vector_type(4)));

// Fused single kernel, barrier-free until the final cross-half combine.
// Block = 256 threads: tid&127 -> p-quad slot, tid>>7 -> expert half (0..7 / 8..15).
// Prologue is PER-WAVE (shfl only): w[e], scale, mask-dtype flag.
//   flag: 0 = 1-byte bool/uint8, 1 = int32, 2 = float32

__global__ __launch_bounds__(256, 4) void cfa_fused(
    const float* __restrict__ V,
    const void* __restrict__ masks,
    const float* __restrict__ betas,
    const float* __restrict__ embed,
    const float* __restrict__ temp,
    float* __restrict__ out)
{
    __shared__ float4 redA[128];
    __shared__ float4 redD[128];

    const int tid  = threadIdx.x;
    const int lane = tid & 63;

    const int q  = blockIdx.x * 128 + (tid & 127);  // global p-quad id [0, 131072)
    const int b  = q >> 14;                         // NP/4 = 16384 quads per b
    const int p  = (q & 16383) << 2;
    const int e0 = (tid >> 7) << 3;                 // 0 or 8 (wave-uniform)

    // ---- issue first expert's V loads immediately (depend on nothing) ----
    const float* vb  = V + b * NP + p;
    const float* ve0 = vb + e0 * (ND * NB * NP);
    f32x4 pre[ND];
    #pragma unroll
    for (int d = 0; d < ND; ++d)
        pre[d] = __builtin_nontemporal_load((const f32x4*)(ve0 + d * (NB * NP)));

    // ---- per-wave prologue (no barrier) ----
    // mask dtype flag from first 256 B (each wave redundantly; L2 broadcast).
    // bool/u8 0/1: some byte1 nonzero. f32 0.0/1.0 LE: byte3==0x3F for 1.0.
    // int32 0/1 LE: bytes 1,3 always zero.
    unsigned mx = ((const unsigned*)masks)[lane];
    unsigned o1 = mx & 0x0000FF00u, o3 = mx & 0xFF000000u;
    #pragma unroll
    for (int off = 32; off; off >>= 1) {
        o1 |= __shfl_xor(o1, off, 64);
        o3 |= __shfl_xor(o3, off, 64);
    }
    const int flag = o1 ? 0 : (o3 ? 2 : 1);

    // w[e]: 4 lanes per expert. lane -> e = lane>>2, r = lane&3.
    {
        const int e = lane >> 2, r = lane & 3;
        const float4* ep = (const float4*)(embed + e * EDIM + r * 32);
        float s = 0.f;
        #pragma unroll
        for (int i = 0; i < 8; ++i) { float4 v = ep[i]; s += v.x + v.y + v.z + v.w; }
        s += __shfl_xor(s, 1, 64);
        s += __shfl_xor(s, 2, 64);
        float bsig = 1.f / (1.f + __expf(-betas[e * NBETAS + r]));
        bsig += __shfl_xor(bsig, 1, 64);
        bsig += __shfl_xor(bsig, 2, 64);
        float pos_w = 1.f / (1.f + __expf(-s * (1.f / EDIM)));
        float wfull = pos_w * (1.f + bsig * (1.f / NBETAS));
        // gather this wave's 8 expert weights (e0 wave-uniform)
        float wv[8];
        #pragma unroll
        for (int ee = 0; ee < 8; ++ee)
            wv[ee] = __shfl(wfull, (e0 + ee) << 2, 64);

        const float scale = 0.2f / fabsf(temp[0]);

        // ---- masks for this thread's 8 experts ----
        float4 wm[8];
        if (flag == 0) {
            const unsigned char* mb = (const unsigned char*)masks + p;
            #pragma unroll
            for (int ee = 0; ee < 8; ++ee) {
                uchar4 u = *(const uchar4*)(mb + (e0 + ee) * NP);
                wm[ee].x = wv[ee] * (float)u.x; wm[ee].y = wv[ee] * (float)u.y;
                wm[ee].z = wv[ee] * (float)u.z; wm[ee].w = wv[ee] * (float)u.w;
            }
        } else if (flag == 1) {
            const int* mi = (const int*)masks + p;
            #pragma unroll
            for (int ee = 0; ee < 8; ++ee) {
                int4 u = *(const int4*)(mi + (e0 + ee) * NP);
                wm[ee].x = wv[ee] * (float)u.x; wm[ee].y = wv[ee] * (float)u.y;
                wm[ee].z = wv[ee] * (float)u.z; wm[ee].w = wv[ee] * (float)u.w;
            }
        } else {
            const float* mf = (const float*)masks + p;
            #pragma unroll
            for (int ee = 0; ee < 8; ++ee) {
                float4 u = *(const float4*)(mf + (e0 + ee) * NP);
                wm[ee].x = wv[ee] * u.x; wm[ee].y = wv[ee] * u.y;
                wm[ee].z = wv[ee] * u.z; wm[ee].w = wv[ee] * u.w;
            }
        }

        float4 den = {0.f, 0.f, 0.f, 0.f};
        #pragma unroll
        for (int ee = 0; ee < 8; ++ee) {
            den.x += wm[ee].x; den.y += wm[ee].y;
            den.z += wm[ee].z; den.w += wm[ee].w;
        }

        // ---- consume prefetched expert e0, then stream the rest ----
        float4 a = {0.f, 0.f, 0.f, 0.f};
        #pragma unroll
        for (int d = 0; d < ND; ++d) {
            a.x = fmaf(wm[0].x, pre[d].x, a.x);
            a.y = fmaf(wm[0].y, pre[d].y, a.y);
            a.z = fmaf(wm[0].z, pre[d].z, a.z);
            a.w = fmaf(wm[0].w, pre[d].w, a.w);
        }
        #pragma unroll
        for (int ee = 1; ee < 8; ++ee) {
            const float* ve = vb + (e0 + ee) * (ND * NB * NP);
            #pragma unroll
            for (int d = 0; d < ND; ++d) {
                f32x4 v = __builtin_nontemporal_load((const f32x4*)(ve + d * (NB * NP)));
                a.x = fmaf(wm[ee].x, v.x, a.x);
                a.y = fmaf(wm[ee].y, v.y, a.y);
                a.z = fmaf(wm[ee].z, v.z, a.z);
                a.w = fmaf(wm[ee].w, v.w, a.w);
            }
        }

        // ---- combine halves via LDS, lower half finalizes ----
        if (tid >= 128) {
            redA[tid - 128] = a;
            redD[tid - 128] = den;
        }
        __syncthreads();
        if (tid < 128) {
            float4 a2 = redA[tid], d2 = redD[tid];
            a.x += a2.x; a.y += a2.y; a.z += a2.z; a.w += a2.w;
            den.x += d2.x; den.y += d2.y; den.z += d2.z; den.w += d2.w;
            float4 o;
            o.x = a.x / fmaxf(den.x, 1e-6f) * scale;
            o.y = a.y / fmaxf(den.y, 1e-6f) * scale;
            o.z = a.z / fmaxf(den.z, 1e-6f) * scale;
            o.w = a.w / fmaxf(den.w, 1e-6f) * scale;
            *(float4*)(out + b * NP + p) = o;
        }
    }
}

extern "C" void kernel_launch(void* const* d_in, const int* in_sizes, int n_in,
                              void* d_out, int out_size, void* d_ws, size_t ws_size,
                              hipStream_t stream) {
    const float* V     = (const float*)d_in[0];
    const void*  masks = d_in[1];
    const float* betas = (const float*)d_in[2];
    const float* embed = (const float*)d_in[3];
    const float* temp  = (const float*)d_in[4];

    float* out = (float*)d_out;

    const int blocks = (NB * NP / 4) / 128;   // 1024
    cfa_fused<<<blocks, 256, 0, stream>>>(V, masks, betas, embed, temp, out);
}